// Round 5
// baseline (1032.196 us; speedup 1.0000x reference)
//
#include <hip/hip_runtime.h>
#include <math.h>

#define N_MEM 100000
#define NP    100352      // 49 * 2048 (padded)
#define NCH   49
#define CHUNK 2048
#define CAP   128
#define NCAND 64          // re-rank set size (wide superset)

__device__ __forceinline__ float softplusf_(float x){ return log1pf(expf(x)); }

__device__ __forceinline__ float wave_sum(float v){
  #pragma unroll
  for (int o=32;o;o>>=1) v += __shfl_xor(v, o, 64);
  return v;
}
__device__ __forceinline__ double wave_sum_d(double v){
  #pragma unroll
  for (int o=32;o;o>>=1) v += __shfl_xor(v, o, 64);
  return v;
}

// argmax carrying (value, global-index tie-break, position meta)
__device__ __forceinline__ void wave_argmax3(float& v, int& j, int& p){
  #pragma unroll
  for (int o=32;o;o>>=1){
    float ov = __shfl_xor(v, o, 64);
    int   oj = __shfl_xor(j, o, 64);
    int   op = __shfl_xor(p, o, 64);
    if (ov > v || (ov == v && oj < j)) { v = ov; j = oj; p = op; }
  }
}

// ---------------- K1: memory embeddings -> mwT (64 x NP), mm  (fp32 stream path;
// candidate generation only — final selection re-derived in K4)
__global__ __launch_bounds__(128) void k1_mem(
    const float* __restrict__ mi,
    const float* __restrict__ w1, const float* __restrict__ b1,
    const float* __restrict__ w2, const float* __restrict__ b2,
    const float* __restrict__ fw,
    float* __restrict__ mwT, float* __restrict__ mm)
{
  __shared__ float xs[64*128];
  int t = threadIdx.x;
  int j = blockIdx.x*128 + t;
  bool real = (j < N_MEM);
  {
    const float4* xp = (const float4*)(mi + (size_t)(real ? j : 0)*64);
    #pragma unroll
    for (int k=0;k<16;k++){
      float4 v = xp[k];
      xs[(4*k+0)*128 + t] = v.x;
      xs[(4*k+1)*128 + t] = v.y;
      xs[(4*k+2)*128 + t] = v.z;
      xs[(4*k+3)*128 + t] = v.w;
    }
  }
  float h[64];
  #pragma unroll
  for (int e=0;e<64;e++) h[e] = b1[e];
  for (int d=0; d<64; d++){
    float xv = xs[d*128 + t];
    #pragma unroll
    for (int e=0;e<64;e++) h[e] = fmaf(xv, w1[d*64+e], h[e]);
  }
  #pragma unroll
  for (int e=0;e<64;e++){ h[e] = fmaxf(h[e], 0.f); xs[e*128 + t] = h[e]; }
  float o[64];
  #pragma unroll
  for (int e=0;e<64;e++) o[e] = b2[e];
  for (int d=0; d<64; d++){
    float hv = xs[d*128 + t];
    #pragma unroll
    for (int e=0;e<64;e++) o[e] = fmaf(hv, w2[d*64+e], o[e]);
  }
  float s2 = 0.f;
  #pragma unroll
  for (int e=0;e<64;e++){
    float sw = sqrtf(softplusf_(fw[e]) + 1e-9f);
    float v = real ? o[e]*sw : 0.f;
    s2 = fmaf(v, v, s2);
    mwT[(size_t)e*NP + j] = v;
  }
  mm[j] = real ? s2 : 3.0e38f;
}

// ---------------- K2: per-query: f64 local embedding + global path + gate
__global__ __launch_bounds__(64) void k2_query(
  const float* __restrict__ x,
  const float* __restrict__ le_w1, const float* __restrict__ le_b1,
  const float* __restrict__ le_w2, const float* __restrict__ le_b2,
  const float* __restrict__ fw,
  const float* __restrict__ ge_w1, const float* __restrict__ ge_b1,
  const float* __restrict__ ge_w2, const float* __restrict__ ge_b2,
  const float* __restrict__ ge_w3, const float* __restrict__ ge_b3,
  const float* __restrict__ gr_w1, const float* __restrict__ gr_b1,
  const float* __restrict__ gr_w2, const float* __restrict__ gr_b2,
  const float* __restrict__ ga_w1, const float* __restrict__ ga_b1,
  const float* __restrict__ ga_w2, const float* __restrict__ ga_b2,
  float* __restrict__ qwf, double* __restrict__ qwd,
  double* __restrict__ qqd, double* __restrict__ ggd, double* __restrict__ gpd)
{
  int l = threadIdx.x, q = blockIdx.x;
  __shared__ double xs[64], qe[64], h1[128], t1[64], t2[64];
  xs[l] = (double)x[q*64+l];
  __syncthreads();
  double a = (double)le_b1[l];
  for (int d=0; d<64; d++) a = fma(xs[d], (double)le_w1[d*64+l], a);
  t1[l] = a > 0.0 ? a : 0.0;
  __syncthreads();
  a = (double)le_b2[l];
  for (int d=0; d<64; d++) a = fma(t1[d], (double)le_w2[d*64+l], a);
  qe[l] = a;
  double sw = sqrt(log1p(exp((double)fw[l])) + 1e-9);
  double qv = a * sw;
  qwd[q*64+l] = qv;
  qwf[q*64+l] = (float)qv;
  double ss = wave_sum_d(qv*qv);
  if (l==0) qqd[q] = ss;
  // ge layer1 (128 wide)
  double a0 = (double)ge_b1[l], a1 = (double)ge_b1[64+l];
  for (int d=0; d<64; d++){
    double xv = xs[d];
    a0 = fma(xv, (double)ge_w1[d*128+l],    a0);
    a1 = fma(xv, (double)ge_w1[d*128+64+l], a1);
  }
  h1[l] = a0>0.0?a0:0.0; h1[64+l] = a1>0.0?a1:0.0;
  __syncthreads();
  a = (double)ge_b2[l];
  for (int d=0; d<128; d++) a = fma(h1[d], (double)ge_w2[d*64+l], a);
  __syncthreads();
  t1[l] = a>0.0?a:0.0;
  __syncthreads();
  a = (double)ge_b3[l];
  for (int d=0; d<64; d++) a = fma(t1[d], (double)ge_w3[d*64+l], a);
  t2[l] = a;                // global_repr
  __syncthreads();
  a = (double)gr_b1[l];
  for (int d=0; d<64; d++) a = fma(t2[d], (double)gr_w1[d*64+l], a);
  __syncthreads();
  t1[l] = a>0.0?a:0.0;
  __syncthreads();
  if (l < 8){
    double b = (double)gr_b2[l];
    for (int d=0; d<64; d++) b = fma(t1[d], (double)gr_w2[d*8+l], b);
    gpd[q*8+l] = b;
  }
  a = (double)ga_b1[l];
  for (int d=0; d<64; d++) a = fma(t2[d], (double)ga_w1[d*64+l], a);
  for (int d=0; d<64; d++) a = fma(qe[d], (double)ga_w1[(64+d)*64+l], a);
  a = a>0.0?a:0.0;
  double p = wave_sum_d(a * (double)ga_w2[l]);
  if (l==0) ggd[q] = 1.0/(1.0 + exp(-(p + (double)ga_b2[0])));
}

// ---------------- K_tau_a: exact fp32 top-16 per (query, 512-subchunk), j in [0,4096)
__global__ __launch_bounds__(256) void k_tau_a(
    const float* __restrict__ mwT, const float* __restrict__ mm,
    const float* __restrict__ qw,
    float* __restrict__ tpv, int* __restrict__ tpi)
{
  int t = threadIdx.x, w = t>>6, lane = t&63;
  int q0 = blockIdx.x*32;
  int jb = blockIdx.y*512;
  __shared__ float qs[2048];
  for (int i=t; i<2048; i+=256){
    int qrel = i>>6, d = i&63;
    qs[(qrel>>3)*512 + d*8 + (qrel&7)] = qw[q0*64 + i];
  }
  __syncthreads();
  float s[8][8];
  #pragma unroll
  for (int a=0;a<8;a++){
    #pragma unroll
    for (int b=0;b<8;b++) s[a][b]=0.f;
  }
  #pragma unroll 4
  for (int d=0; d<64; d++){
    const float* row = mwT + (size_t)d*NP + jb + 4*lane;
    float4 m0 = *(const float4*)row;
    float4 m1 = *(const float4*)(row + 256);
    const float* qp = qs + w*512 + d*8;
    float4 qA = *(const float4*)qp;
    float4 qB = *(const float4*)(qp+4);
    float qvv[8] = {qA.x,qA.y,qA.z,qA.w,qB.x,qB.y,qB.z,qB.w};
    float mvv[8] = {m0.x,m0.y,m0.z,m0.w,m1.x,m1.y,m1.z,m1.w};
    #pragma unroll
    for (int qi=0;qi<8;qi++){
      #pragma unroll
      for (int jj=0;jj<8;jj++) s[qi][jj] = fmaf(qvv[qi], mvv[jj], s[qi][jj]);
    }
  }
  float4 mmA = *(const float4*)(mm + jb + 4*lane);
  float4 mmB = *(const float4*)(mm + jb + 256 + 4*lane);
  float mmv[8] = {mmA.x,mmA.y,mmA.z,mmA.w,mmB.x,mmB.y,mmB.z,mmB.w};
  for (int qi=0; qi<8; qi++){
    float sc[8];
    #pragma unroll
    for (int jj=0;jj<8;jj++) sc[jj] = 2.f*s[qi][jj] - mmv[jj];
    unsigned used = 0u;
    for (int it=0; it<16; it++){
      float v = -3.0e38f; int slot = 0; int jwin = jb + 4*lane;
      #pragma unroll
      for (int jj=0;jj<8;jj++){
        bool ok = !((used>>jj)&1u);
        int jg = jb + ((jj<4)? (4*lane+jj) : (256+4*lane+jj-4));
        if (ok && sc[jj] > v){ v = sc[jj]; slot = jj; jwin = jg; }
      }
      float rv = v; int rj = jwin; int rp = lane*8 + slot;
      wave_argmax3(rv, rj, rp);
      if ((rp>>3) == lane) used |= 1u << (rp&7);
      if (lane == it){
        int o = (q0 + w*8 + qi)*128 + blockIdx.y*16 + it;
        tpv[o] = rv; tpi[o] = rj;
      }
    }
  }
}

// ---------------- K_tau_b: tau = 16th of 4096-sample; candidates for chunks 0,1
__global__ __launch_bounds__(64) void k_tau_b(
    const float* __restrict__ tpv, const int* __restrict__ tpi,
    float* __restrict__ tau, float* __restrict__ cv, int* __restrict__ ci)
{
  int l = threadIdx.x, q = blockIdx.x;
  float v0 = tpv[q*128 + l];      int i0 = tpi[q*128 + l];
  float v1 = tpv[q*128 + 64 + l]; int i1 = tpi[q*128 + 64 + l];
  __shared__ float sh0[17], sh1[17];
  if (l==0){ sh0[16] = -3.0e38f; sh1[16] = -3.0e38f; }
  bool u0=false, u1=false;
  for (int it=0; it<16; it++){
    float a = u0 ? -3.0e38f : v0; int aj = i0; int ap = l;
    wave_argmax3(a, aj, ap);
    if (ap == l) u0 = true;
    if (l == it){ cv[(q*NCH+0)*16+it] = a; ci[(q*NCH+0)*16+it] = aj; sh0[it] = a; }
  }
  for (int it=0; it<16; it++){
    float a = u1 ? -3.0e38f : v1; int aj = i1; int ap = l;
    wave_argmax3(a, aj, ap);
    if (ap == l) u1 = true;
    if (l == it){ cv[(q*NCH+1)*16+it] = a; ci[(q*NCH+1)*16+it] = aj; sh1[it] = a; }
  }
  __syncthreads();
  if (l==0){
    int a=0,b=0; float val = -3.0e38f;
    for (int k=0;k<16;k++){ val = (sh0[a] >= sh1[b]) ? sh0[a++] : sh1[b++]; }
    tau[q] = val;
  }
}

// ---------------- K3: chunks 2..48, filter >= tau - margin, per-chunk fp32 top-16
__global__ __launch_bounds__(256) void k3_main(
    const float* __restrict__ mwT, const float* __restrict__ mm,
    const float* __restrict__ qw,  const float* __restrict__ tau,
    float* __restrict__ cv, int* __restrict__ ci)
{
  int t=threadIdx.x, w=t>>6, lane=t&63;
  int q0 = blockIdx.x*32;
  int c  = blockIdx.y + 2;
  __shared__ float qs[2048];
  __shared__ float av[32][CAP];
  __shared__ int   ai[32][CAP];
  __shared__ int   cnt[32];
  __shared__ float taus[32];
  for (int i=t; i<2048; i+=256){
    int qrel=i>>6, d=i&63;
    qs[(qrel>>3)*512 + d*8 + (qrel&7)] = qw[q0*64 + i];
  }
  if (t < 32){ cnt[t]=0; taus[t]=tau[q0+t] - 5e-6f; }   // margin covers fp32 stream noise
  __syncthreads();
  for (int sub=0; sub<4; sub++){
    int jb = c*CHUNK + sub*512;
    float s[8][8];
    #pragma unroll
    for (int a=0;a<8;a++){
      #pragma unroll
      for (int b=0;b<8;b++) s[a][b]=0.f;
    }
    #pragma unroll 4
    for (int d=0; d<64; d++){
      const float* row = mwT + (size_t)d*NP + jb + 4*lane;
      float4 m0 = *(const float4*)row;
      float4 m1 = *(const float4*)(row + 256);
      const float* qp = qs + w*512 + d*8;
      float4 qA = *(const float4*)qp;
      float4 qB = *(const float4*)(qp+4);
      float qvv[8] = {qA.x,qA.y,qA.z,qA.w,qB.x,qB.y,qB.z,qB.w};
      float mvv[8] = {m0.x,m0.y,m0.z,m0.w,m1.x,m1.y,m1.z,m1.w};
      #pragma unroll
      for (int qi=0;qi<8;qi++){
        #pragma unroll
        for (int jj=0;jj<8;jj++) s[qi][jj] = fmaf(qvv[qi], mvv[jj], s[qi][jj]);
      }
    }
    float4 mmA = *(const float4*)(mm + jb + 4*lane);
    float4 mmB = *(const float4*)(mm + jb + 256 + 4*lane);
    float mmv[8] = {mmA.x,mmA.y,mmA.z,mmA.w,mmB.x,mmB.y,mmB.z,mmB.w};
    #pragma unroll
    for (int qi=0;qi<8;qi++){
      float tq = taus[w*8+qi];
      #pragma unroll
      for (int jj=0;jj<8;jj++){
        float sc = 2.f*s[qi][jj] - mmv[jj];
        if (sc >= tq){
          int p = atomicAdd(&cnt[w*8+qi], 1);
          if (p < CAP){
            av[w*8+qi][p] = sc;
            ai[w*8+qi][p] = jb + ((jj<4)?(4*lane+jj):(256+4*lane+jj-4));
          }
        }
      }
    }
  }
  __syncthreads();
  for (int qi=0; qi<8; qi++){
    int qi_ = w*8 + qi;
    int n = cnt[qi_] < CAP ? cnt[qi_] : CAP;
    float v0 = (lane    < n)? av[qi_][lane]    : -3.0e38f;
    int   i0 = (lane    < n)? ai[qi_][lane]    : 0x7fffffff;
    float v1 = (lane+64 < n)? av[qi_][lane+64] : -3.0e38f;
    int   i1 = (lane+64 < n)? ai[qi_][lane+64] : 0x7fffffff;
    bool u0=false, u1=false;
    for (int it=0; it<16; it++){
      float a0 = u0 ? -3.0e38f : v0;
      float a1 = u1 ? -3.0e38f : v1;
      float v; int j; int p;
      if (a0 > a1 || (a0 == a1 && i0 <= i1)) { v=a0; j=i0; p=lane*2; }
      else                                   { v=a1; j=i1; p=lane*2+1; }
      wave_argmax3(v, j, p);
      if ((p>>1) == lane){ if (p&1) u1=true; else u0=true; }
      if (lane == it){
        int o = ((q0+qi_)*NCH + c)*16 + it;
        cv[o]=v; ci[o]=j;
      }
    }
  }
}

// ---------------- K4: top-64 merge -> f64 d2 -> f32-quantized raw -> (raw desc, idx asc)
//                  top-16 -> softmax/gather/blend/refine
__global__ __launch_bounds__(64) void k4_final(
    const float* __restrict__ cv, const int* __restrict__ ci,
    const double* __restrict__ qwd_g, const double* __restrict__ qqd_g,
    const double* __restrict__ ggd_g, const double* __restrict__ gpd_g,
    const float* __restrict__ mi, const float* __restrict__ mt,
    const float* __restrict__ le_w1, const float* __restrict__ le_b1,
    const float* __restrict__ le_w2, const float* __restrict__ le_b2,
    const float* __restrict__ fw, const float* __restrict__ itp,
    const float* __restrict__ rw1, const float* __restrict__ rb1,
    const float* __restrict__ rw2, const float* __restrict__ rb2,
    float* __restrict__ out)
{
  int l = threadIdx.x, q = blockIdx.x;
  __shared__ float  sv[NCH*16];
  __shared__ int    si[NCH*16];
  __shared__ int    cidx[NCAND];
  __shared__ double md[64], hd[64];
  __shared__ double cd2[NCAND];
  __shared__ float  craw[NCAND];
  __shared__ float  selr[16];
  __shared__ int    selj[16];
  __shared__ double hh[32];
  for (int i=l; i<NCH*16; i+=64){ sv[i]=cv[q*NCH*16+i]; si[i]=ci[q*NCH*16+i]; }
  __syncthreads();
  // top-64 by fp32 stream scores (wide superset; includes all near-boundary ties)
  for (int it=0; it<NCAND; it++){
    float v=-3.0e38f; int j=0x7fffffff; int pos=-1;
    for (int i=l; i<NCH*16; i+=64){
      float xx = sv[i];
      if (xx > v || (xx == v && si[i] < j)){ v=xx; j=si[i]; pos=i; }
    }
    float rv=v; int rj=j, rp=pos;
    wave_argmax3(rv, rj, rp);
    if (l==it) cidx[it]=rj;
    if (l==0 && rp >= 0) sv[rp] = -3.0e38f;
    __syncthreads();
  }
  // f64 re-rank: recompute candidate memory embeddings + d2 in double
  double qwl = qwd_g[q*64+l];
  double swl = sqrt(log1p(exp((double)fw[l])) + 1e-9);
  double qq  = qqd_g[q];
  for (int c=0; c<NCAND; c++){
    int jraw = cidx[c];
    int js = ((unsigned)jraw < (unsigned)N_MEM) ? jraw : 0;   // OOB guard (padded cand)
    md[l] = (double)mi[(size_t)js*64 + l];
    __syncthreads();
    double a0=0,a1=0,a2=0,a3=0;
    for (int d=0; d<64; d+=4){
      a0 = fma(md[d  ], (double)le_w1[(d  )*64+l], a0);
      a1 = fma(md[d+1], (double)le_w1[(d+1)*64+l], a1);
      a2 = fma(md[d+2], (double)le_w1[(d+2)*64+l], a2);
      a3 = fma(md[d+3], (double)le_w1[(d+3)*64+l], a3);
    }
    double h = (a0+a1)+(a2+a3) + (double)le_b1[l];
    h = h>0.0 ? h : 0.0;
    __syncthreads();
    hd[l] = h;
    __syncthreads();
    a0=a1=a2=a3=0;
    for (int d=0; d<64; d+=4){
      a0 = fma(hd[d  ], (double)le_w2[(d  )*64+l], a0);
      a1 = fma(hd[d+1], (double)le_w2[(d+1)*64+l], a1);
      a2 = fma(hd[d+2], (double)le_w2[(d+2)*64+l], a2);
      a3 = fma(hd[d+3], (double)le_w2[(d+3)*64+l], a3);
    }
    double o  = (a0+a1)+(a2+a3) + (double)le_b2[l];
    double mw = o * swl;
    double mm = wave_sum_d(mw*mw);
    double dt = wave_sum_d(mw*qwl);
    if (l==0) cd2[c] = qq + mm - 2.0*dt;
    __syncthreads();
  }
  // f32-quantized raw activations (emulates np's exp32 compression of d2 ties)
  {
    float e32  = (float)exp((double)itp[0]);
    float sp32 = (float)log1p((double)e32);
    float t32  = __fadd_rn(sp32, 1e-9f);      // temp = softplus + EPS
    float dn32 = __fadd_rn(t32, 1e-9f);       // denom = temp + EPS
    double denom = (double)dn32;
    if (l < NCAND){
      double d2 = cd2[l]; if (d2 < 0.0) d2 = 0.0;
      bool ok = (unsigned)cidx[l] < (unsigned)N_MEM;
      float ratio32 = (float)(d2 / denom);
      craw[l] = ok ? (float)exp(-(double)ratio32) : -1.0f;
    }
  }
  __syncthreads();
  // top-16 by (raw32 desc, index asc) — matches np float32 top_k incl. quantized ties
  {
    float rme = (l < NCAND) ? craw[l] : -2.0f;
    int   jme = (l < NCAND && (unsigned)cidx[l] < (unsigned)N_MEM) ? cidx[l] : 0x7fffffff;
    bool used = false;
    for (int it=0; it<16; it++){
      float a = used ? -2.0f : rme; int aj = jme; int ap = l;
      wave_argmax3(a, aj, ap);
      if (ap == l) used = true;
      if (l == it){ selr[it]=a; selj[it]=aj; }
    }
  }
  __syncthreads();
  // f64 softmax over the f32-quantized raws (smooth; bf16 compare absorbs)
  double raw = (l<16) ? (double)selr[l] : -1.0e300;
  double mv = raw;
  #pragma unroll
  for (int o=32;o;o>>=1){ double ov = __shfl_xor(mv,o,64); mv = ov>mv?ov:mv; }
  double e  = (l<16) ? exp(raw - mv) : 0.0;
  double se = wave_sum_d(e);
  double wgt = e / se;
  double lp[8] = {0,0,0,0,0,0,0,0};
  if (l < 16){
    const float* tr = mt + (size_t)selj[l]*8;
    #pragma unroll
    for (int tt=0; tt<8; tt++) lp[tt] = wgt * (double)tr[tt];
  }
  #pragma unroll
  for (int tt=0; tt<8; tt++) lp[tt] = wave_sum_d(lp[tt]);
  double g = ggd_g[q];
  double bl[8];
  #pragma unroll
  for (int tt=0; tt<8; tt++) bl[tt] = g*lp[tt] + (1.0-g)*gpd_g[q*8+tt];
  if (l < 32){
    double a = (double)rb1[l];
    #pragma unroll
    for (int tt=0; tt<8; tt++) a = fma(bl[tt], (double)rw1[tt*32+l], a);
    hh[l] = a>0.0?a:0.0;
  }
  __syncthreads();
  if (l < 8){
    double a = (double)rb2[l];
    #pragma unroll
    for (int i=0; i<32; i++) a = fma(hh[i], (double)rw2[i*8+l], a);
    out[q*8+l] = (float)a;
  }
}

extern "C" void kernel_launch(void* const* d_in, const int* in_sizes, int n_in,
                              void* d_out, int out_size, void* d_ws, size_t ws_size,
                              hipStream_t stream)
{
  const float* x     = (const float*)d_in[0];
  const float* mi    = (const float*)d_in[1];
  const float* mt    = (const float*)d_in[2];
  const float* le_w1 = (const float*)d_in[3];
  const float* le_b1 = (const float*)d_in[4];
  const float* le_w2 = (const float*)d_in[5];
  const float* le_b2 = (const float*)d_in[6];
  const float* fw    = (const float*)d_in[7];
  const float* itp   = (const float*)d_in[8];
  const float* ge_w1 = (const float*)d_in[9];
  const float* ge_b1 = (const float*)d_in[10];
  const float* ge_w2 = (const float*)d_in[11];
  const float* ge_b2 = (const float*)d_in[12];
  const float* ge_w3 = (const float*)d_in[13];
  const float* ge_b3 = (const float*)d_in[14];
  const float* gr_w1 = (const float*)d_in[15];
  const float* gr_b1 = (const float*)d_in[16];
  const float* gr_w2 = (const float*)d_in[17];
  const float* gr_b2 = (const float*)d_in[18];
  const float* ga_w1 = (const float*)d_in[19];
  const float* ga_b1 = (const float*)d_in[20];
  const float* ga_w2 = (const float*)d_in[21];
  const float* ga_b2 = (const float*)d_in[22];
  const float* rh_w1 = (const float*)d_in[23];
  const float* rh_b1 = (const float*)d_in[24];
  const float* rh_w2 = (const float*)d_in[25];
  const float* rh_b2 = (const float*)d_in[26];

  // doubles first (8B alignment), then float/int region
  double* dws = (double*)d_ws;
  double* qwd = dws;                                // 1024*64
  double* qqd = qwd + (size_t)1024*64;              // 1024
  double* ggd = qqd + 1024;                         // 1024
  double* gpd = ggd + 1024;                         // 8192
  float*  fws = (float*)(gpd + 8192);
  float* mwT = fws;                                 // 64*NP
  float* mm  = mwT + (size_t)64*NP;                 // NP
  float* qwf = mm  + NP;                            // 1024*64
  float* tau = qwf + (size_t)1024*64;               // 1024
  float* tpv = tau + 1024;                          // 1024*128
  int*   tpi = (int*)(tpv + (size_t)1024*128);      // 1024*128
  float* cv  = (float*)(tpi + (size_t)1024*128);    // 1024*49*16
  int*   ci  = (int*)(cv + (size_t)1024*NCH*16);    // 1024*49*16

  k1_mem   <<<dim3(NP/128), dim3(128), 0, stream>>>(mi, le_w1, le_b1, le_w2, le_b2, fw, mwT, mm);
  k2_query <<<dim3(1024),   dim3(64),  0, stream>>>(x, le_w1, le_b1, le_w2, le_b2, fw,
                ge_w1, ge_b1, ge_w2, ge_b2, ge_w3, ge_b3,
                gr_w1, gr_b1, gr_w2, gr_b2,
                ga_w1, ga_b1, ga_w2, ga_b2,
                qwf, qwd, qqd, ggd, gpd);
  k_tau_a  <<<dim3(32,8),   dim3(256), 0, stream>>>(mwT, mm, qwf, tpv, tpi);
  k_tau_b  <<<dim3(1024),   dim3(64),  0, stream>>>(tpv, tpi, tau, cv, ci);
  k3_main  <<<dim3(32,47),  dim3(256), 0, stream>>>(mwT, mm, qwf, tau, cv, ci);
  k4_final <<<dim3(1024),   dim3(64),  0, stream>>>(cv, ci, qwd, qqd, ggd, gpd, mi, mt,
                le_w1, le_b1, le_w2, le_b2, fw, itp,
                rh_w1, rh_b1, rh_w2, rh_b2, (float*)d_out);
}

// Round 6
// 875.487 us; speedup vs baseline: 1.1790x; 1.1790x over previous
//
#include <hip/hip_runtime.h>
#include <math.h>

#define N_MEM 100000
#define NP    100352      // 49 * 2048 (padded)
#define NCH   49
#define CHUNK 2048
#define CAP   128
#define NCAND 64          // max re-rank set size

__device__ __forceinline__ float softplusf_(float x){ return log1pf(expf(x)); }

__device__ __forceinline__ float wave_sum(float v){
  #pragma unroll
  for (int o=32;o;o>>=1) v += __shfl_xor(v, o, 64);
  return v;
}
__device__ __forceinline__ double wave_sum_d(double v){
  #pragma unroll
  for (int o=32;o;o>>=1) v += __shfl_xor(v, o, 64);
  return v;
}

// argmax carrying (value, global-index tie-break, position meta)
__device__ __forceinline__ void wave_argmax3(float& v, int& j, int& p){
  #pragma unroll
  for (int o=32;o;o>>=1){
    float ov = __shfl_xor(v, o, 64);
    int   oj = __shfl_xor(j, o, 64);
    int   op = __shfl_xor(p, o, 64);
    if (ov > v || (ov == v && oj < j)) { v = ov; j = oj; p = op; }
  }
}

// ---------------- K1: memory embeddings -> mwT (64 x NP), mm  (fp32 stream path)
__global__ __launch_bounds__(128) void k1_mem(
    const float* __restrict__ mi,
    const float* __restrict__ w1, const float* __restrict__ b1,
    const float* __restrict__ w2, const float* __restrict__ b2,
    const float* __restrict__ fw,
    float* __restrict__ mwT, float* __restrict__ mm)
{
  __shared__ float xs[64*128];
  int t = threadIdx.x;
  int j = blockIdx.x*128 + t;
  bool real = (j < N_MEM);
  {
    const float4* xp = (const float4*)(mi + (size_t)(real ? j : 0)*64);
    #pragma unroll
    for (int k=0;k<16;k++){
      float4 v = xp[k];
      xs[(4*k+0)*128 + t] = v.x;
      xs[(4*k+1)*128 + t] = v.y;
      xs[(4*k+2)*128 + t] = v.z;
      xs[(4*k+3)*128 + t] = v.w;
    }
  }
  float h[64];
  #pragma unroll
  for (int e=0;e<64;e++) h[e] = b1[e];
  for (int d=0; d<64; d++){
    float xv = xs[d*128 + t];
    #pragma unroll
    for (int e=0;e<64;e++) h[e] = fmaf(xv, w1[d*64+e], h[e]);
  }
  #pragma unroll
  for (int e=0;e<64;e++){ h[e] = fmaxf(h[e], 0.f); xs[e*128 + t] = h[e]; }
  float o[64];
  #pragma unroll
  for (int e=0;e<64;e++) o[e] = b2[e];
  for (int d=0; d<64; d++){
    float hv = xs[d*128 + t];
    #pragma unroll
    for (int e=0;e<64;e++) o[e] = fmaf(hv, w2[d*64+e], o[e]);
  }
  float s2 = 0.f;
  #pragma unroll
  for (int e=0;e<64;e++){
    float sw = sqrtf(softplusf_(fw[e]) + 1e-9f);
    float v = real ? o[e]*sw : 0.f;
    s2 = fmaf(v, v, s2);
    mwT[(size_t)e*NP + j] = v;
  }
  mm[j] = real ? s2 : 3.0e38f;
}

// ---------------- K2: per-query: f64 local embedding + global path + gate
__global__ __launch_bounds__(64) void k2_query(
  const float* __restrict__ x,
  const float* __restrict__ le_w1, const float* __restrict__ le_b1,
  const float* __restrict__ le_w2, const float* __restrict__ le_b2,
  const float* __restrict__ fw,
  const float* __restrict__ ge_w1, const float* __restrict__ ge_b1,
  const float* __restrict__ ge_w2, const float* __restrict__ ge_b2,
  const float* __restrict__ ge_w3, const float* __restrict__ ge_b3,
  const float* __restrict__ gr_w1, const float* __restrict__ gr_b1,
  const float* __restrict__ gr_w2, const float* __restrict__ gr_b2,
  const float* __restrict__ ga_w1, const float* __restrict__ ga_b1,
  const float* __restrict__ ga_w2, const float* __restrict__ ga_b2,
  float* __restrict__ qwf, double* __restrict__ qwd,
  double* __restrict__ qqd, double* __restrict__ ggd, double* __restrict__ gpd)
{
  int l = threadIdx.x, q = blockIdx.x;
  __shared__ double xs[64], qe[64], h1[128], t1[64], t2[64];
  xs[l] = (double)x[q*64+l];
  __syncthreads();
  double a = (double)le_b1[l];
  for (int d=0; d<64; d++) a = fma(xs[d], (double)le_w1[d*64+l], a);
  t1[l] = a > 0.0 ? a : 0.0;
  __syncthreads();
  a = (double)le_b2[l];
  for (int d=0; d<64; d++) a = fma(t1[d], (double)le_w2[d*64+l], a);
  qe[l] = a;
  double sw = sqrt(log1p(exp((double)fw[l])) + 1e-9);
  double qv = a * sw;
  qwd[q*64+l] = qv;
  qwf[q*64+l] = (float)qv;
  double ss = wave_sum_d(qv*qv);
  if (l==0) qqd[q] = ss;
  // ge layer1 (128 wide)
  double a0 = (double)ge_b1[l], a1 = (double)ge_b1[64+l];
  for (int d=0; d<64; d++){
    double xv = xs[d];
    a0 = fma(xv, (double)ge_w1[d*128+l],    a0);
    a1 = fma(xv, (double)ge_w1[d*128+64+l], a1);
  }
  h1[l] = a0>0.0?a0:0.0; h1[64+l] = a1>0.0?a1:0.0;
  __syncthreads();
  a = (double)ge_b2[l];
  for (int d=0; d<128; d++) a = fma(h1[d], (double)ge_w2[d*64+l], a);
  __syncthreads();
  t1[l] = a>0.0?a:0.0;
  __syncthreads();
  a = (double)ge_b3[l];
  for (int d=0; d<64; d++) a = fma(t1[d], (double)ge_w3[d*64+l], a);
  t2[l] = a;                // global_repr
  __syncthreads();
  a = (double)gr_b1[l];
  for (int d=0; d<64; d++) a = fma(t2[d], (double)gr_w1[d*64+l], a);
  __syncthreads();
  t1[l] = a>0.0?a:0.0;
  __syncthreads();
  if (l < 8){
    double b = (double)gr_b2[l];
    for (int d=0; d<64; d++) b = fma(t1[d], (double)gr_w2[d*8+l], b);
    gpd[q*8+l] = b;
  }
  a = (double)ga_b1[l];
  for (int d=0; d<64; d++) a = fma(t2[d], (double)ga_w1[d*64+l], a);
  for (int d=0; d<64; d++) a = fma(qe[d], (double)ga_w1[(64+d)*64+l], a);
  a = a>0.0?a:0.0;
  double p = wave_sum_d(a * (double)ga_w2[l]);
  if (l==0) ggd[q] = 1.0/(1.0 + exp(-(p + (double)ga_b2[0])));
}

// ---------------- K_tau_a: exact fp32 top-16 per (query, 512-subchunk), j in [0,4096)
__global__ __launch_bounds__(256) void k_tau_a(
    const float* __restrict__ mwT, const float* __restrict__ mm,
    const float* __restrict__ qw,
    float* __restrict__ tpv, int* __restrict__ tpi)
{
  int t = threadIdx.x, w = t>>6, lane = t&63;
  int q0 = blockIdx.x*32;
  int jb = blockIdx.y*512;
  __shared__ float qs[2048];
  for (int i=t; i<2048; i+=256){
    int qrel = i>>6, d = i&63;
    qs[(qrel>>3)*512 + d*8 + (qrel&7)] = qw[q0*64 + i];
  }
  __syncthreads();
  float s[8][8];
  #pragma unroll
  for (int a=0;a<8;a++){
    #pragma unroll
    for (int b=0;b<8;b++) s[a][b]=0.f;
  }
  #pragma unroll 4
  for (int d=0; d<64; d++){
    const float* row = mwT + (size_t)d*NP + jb + 4*lane;
    float4 m0 = *(const float4*)row;
    float4 m1 = *(const float4*)(row + 256);
    const float* qp = qs + w*512 + d*8;
    float4 qA = *(const float4*)qp;
    float4 qB = *(const float4*)(qp+4);
    float qvv[8] = {qA.x,qA.y,qA.z,qA.w,qB.x,qB.y,qB.z,qB.w};
    float mvv[8] = {m0.x,m0.y,m0.z,m0.w,m1.x,m1.y,m1.z,m1.w};
    #pragma unroll
    for (int qi=0;qi<8;qi++){
      #pragma unroll
      for (int jj=0;jj<8;jj++) s[qi][jj] = fmaf(qvv[qi], mvv[jj], s[qi][jj]);
    }
  }
  float4 mmA = *(const float4*)(mm + jb + 4*lane);
  float4 mmB = *(const float4*)(mm + jb + 256 + 4*lane);
  float mmv[8] = {mmA.x,mmA.y,mmA.z,mmA.w,mmB.x,mmB.y,mmB.z,mmB.w};
  for (int qi=0; qi<8; qi++){
    float sc[8];
    #pragma unroll
    for (int jj=0;jj<8;jj++) sc[jj] = 2.f*s[qi][jj] - mmv[jj];
    unsigned used = 0u;
    for (int it=0; it<16; it++){
      float v = -3.0e38f; int slot = 0; int jwin = jb + 4*lane;
      #pragma unroll
      for (int jj=0;jj<8;jj++){
        bool ok = !((used>>jj)&1u);
        int jg = jb + ((jj<4)? (4*lane+jj) : (256+4*lane+jj-4));
        if (ok && sc[jj] > v){ v = sc[jj]; slot = jj; jwin = jg; }
      }
      float rv = v; int rj = jwin; int rp = lane*8 + slot;
      wave_argmax3(rv, rj, rp);
      if ((rp>>3) == lane) used |= 1u << (rp&7);
      if (lane == it){
        int o = (q0 + w*8 + qi)*128 + blockIdx.y*16 + it;
        tpv[o] = rv; tpi[o] = rj;
      }
    }
  }
}

// ---------------- K_tau_b: tau = 16th of 4096-sample; candidates for chunks 0,1
__global__ __launch_bounds__(64) void k_tau_b(
    const float* __restrict__ tpv, const int* __restrict__ tpi,
    float* __restrict__ tau, float* __restrict__ cv, int* __restrict__ ci)
{
  int l = threadIdx.x, q = blockIdx.x;
  float v0 = tpv[q*128 + l];      int i0 = tpi[q*128 + l];
  float v1 = tpv[q*128 + 64 + l]; int i1 = tpi[q*128 + 64 + l];
  __shared__ float sh0[17], sh1[17];
  if (l==0){ sh0[16] = -3.0e38f; sh1[16] = -3.0e38f; }
  bool u0=false, u1=false;
  for (int it=0; it<16; it++){
    float a = u0 ? -3.0e38f : v0; int aj = i0; int ap = l;
    wave_argmax3(a, aj, ap);
    if (ap == l) u0 = true;
    if (l == it){ cv[(q*NCH+0)*16+it] = a; ci[(q*NCH+0)*16+it] = aj; sh0[it] = a; }
  }
  for (int it=0; it<16; it++){
    float a = u1 ? -3.0e38f : v1; int aj = i1; int ap = l;
    wave_argmax3(a, aj, ap);
    if (ap == l) u1 = true;
    if (l == it){ cv[(q*NCH+1)*16+it] = a; ci[(q*NCH+1)*16+it] = aj; sh1[it] = a; }
  }
  __syncthreads();
  if (l==0){
    int a=0,b=0; float val = -3.0e38f;
    for (int k=0;k<16;k++){ val = (sh0[a] >= sh1[b]) ? sh0[a++] : sh1[b++]; }
    tau[q] = val;
  }
}

// ---------------- K3: chunks 2..48, filter >= tau - margin, per-chunk fp32 top-16
__global__ __launch_bounds__(256) void k3_main(
    const float* __restrict__ mwT, const float* __restrict__ mm,
    const float* __restrict__ qw,  const float* __restrict__ tau,
    float* __restrict__ cv, int* __restrict__ ci)
{
  int t=threadIdx.x, w=t>>6, lane=t&63;
  int q0 = blockIdx.x*32;
  int c  = blockIdx.y + 2;
  __shared__ float qs[2048];
  __shared__ float av[32][CAP];
  __shared__ int   ai[32][CAP];
  __shared__ int   cnt[32];
  __shared__ float taus[32];
  for (int i=t; i<2048; i+=256){
    int qrel=i>>6, d=i&63;
    qs[(qrel>>3)*512 + d*8 + (qrel&7)] = qw[q0*64 + i];
  }
  if (t < 32){ cnt[t]=0; taus[t]=tau[q0+t] - 5e-6f; }   // margin covers fp32 stream noise
  __syncthreads();
  for (int sub=0; sub<4; sub++){
    int jb = c*CHUNK + sub*512;
    float s[8][8];
    #pragma unroll
    for (int a=0;a<8;a++){
      #pragma unroll
      for (int b=0;b<8;b++) s[a][b]=0.f;
    }
    #pragma unroll 4
    for (int d=0; d<64; d++){
      const float* row = mwT + (size_t)d*NP + jb + 4*lane;
      float4 m0 = *(const float4*)row;
      float4 m1 = *(const float4*)(row + 256);
      const float* qp = qs + w*512 + d*8;
      float4 qA = *(const float4*)qp;
      float4 qB = *(const float4*)(qp+4);
      float qvv[8] = {qA.x,qA.y,qA.z,qA.w,qB.x,qB.y,qB.z,qB.w};
      float mvv[8] = {m0.x,m0.y,m0.z,m0.w,m1.x,m1.y,m1.z,m1.w};
      #pragma unroll
      for (int qi=0;qi<8;qi++){
        #pragma unroll
        for (int jj=0;jj<8;jj++) s[qi][jj] = fmaf(qvv[qi], mvv[jj], s[qi][jj]);
      }
    }
    float4 mmA = *(const float4*)(mm + jb + 4*lane);
    float4 mmB = *(const float4*)(mm + jb + 256 + 4*lane);
    float mmv[8] = {mmA.x,mmA.y,mmA.z,mmA.w,mmB.x,mmB.y,mmB.z,mmB.w};
    #pragma unroll
    for (int qi=0;qi<8;qi++){
      float tq = taus[w*8+qi];
      #pragma unroll
      for (int jj=0;jj<8;jj++){
        float sc = 2.f*s[qi][jj] - mmv[jj];
        if (sc >= tq){
          int p = atomicAdd(&cnt[w*8+qi], 1);
          if (p < CAP){
            av[w*8+qi][p] = sc;
            ai[w*8+qi][p] = jb + ((jj<4)?(4*lane+jj):(256+4*lane+jj-4));
          }
        }
      }
    }
  }
  __syncthreads();
  for (int qi=0; qi<8; qi++){
    int qi_ = w*8 + qi;
    int n = cnt[qi_] < CAP ? cnt[qi_] : CAP;
    float v0 = (lane    < n)? av[qi_][lane]    : -3.0e38f;
    int   i0 = (lane    < n)? ai[qi_][lane]    : 0x7fffffff;
    float v1 = (lane+64 < n)? av[qi_][lane+64] : -3.0e38f;
    int   i1 = (lane+64 < n)? ai[qi_][lane+64] : 0x7fffffff;
    bool u0=false, u1=false;
    for (int it=0; it<16; it++){
      float a0 = u0 ? -3.0e38f : v0;
      float a1 = u1 ? -3.0e38f : v1;
      float v; int j; int p;
      if (a0 > a1 || (a0 == a1 && i0 <= i1)) { v=a0; j=i0; p=lane*2; }
      else                                   { v=a1; j=i1; p=lane*2+1; }
      wave_argmax3(v, j, p);
      if ((p>>1) == lane){ if (p&1) u1=true; else u0=true; }
      if (lane == it){
        int o = ((q0+qi_)*NCH + c)*16 + it;
        cv[o]=v; ci[o]=j;
      }
    }
  }
}

// ---------------- K4 (restructured): 49-way merge -> threshold compaction ->
// multi-wave f64 re-rank -> f32-quantized select -> softmax/blend/refine
__global__ __launch_bounds__(256) void k4_final(
    const float* __restrict__ cv, const int* __restrict__ ci,
    const double* __restrict__ qwd_g, const double* __restrict__ qqd_g,
    const double* __restrict__ ggd_g, const double* __restrict__ gpd_g,
    const float* __restrict__ mi, const float* __restrict__ mt,
    const float* __restrict__ le_w1, const float* __restrict__ le_b1,
    const float* __restrict__ le_w2, const float* __restrict__ le_b2,
    const float* __restrict__ fw, const float* __restrict__ itp,
    const float* __restrict__ rw1, const float* __restrict__ rb1,
    const float* __restrict__ rw2, const float* __restrict__ rb2,
    float* __restrict__ out)
{
  int t = threadIdx.x, w = t>>6, l = t&63, q = blockIdx.x;
  __shared__ float  svv[NCH*16];
  __shared__ int    sii[NCH*16];
  __shared__ float  v16s;
  __shared__ int    ncnt;
  __shared__ int    candj[NCAND];
  __shared__ double cd2[NCAND];
  __shared__ double mdw[4][64], hdw[4][64];
  __shared__ float  selr[16];
  __shared__ int    selj[16];
  __shared__ double hh[32];
  // Phase A: load candidates
  for (int i=t; i<NCH*16; i+=256){ svv[i]=cv[q*NCH*16+i]; sii[i]=ci[q*NCH*16+i]; }
  if (t==0) ncnt = 0;
  __syncthreads();
  // Phase B (wave 0): exact 16th-largest stream score via 49-way merge of sorted lists
  if (t < 64){
    int pos = 0;
    float last = -3.0e38f;
    for (int it=0; it<16; it++){
      float hv = (t < NCH && pos < 16) ? svv[t*16+pos] : -3.0e38f;
      int hj = t; int hp = t;
      wave_argmax3(hv, hj, hp);     // unique winner via lane tie-break
      if (hp == t) pos++;
      last = hv;
    }
    if (t==0) v16s = last;
  }
  __syncthreads();
  // Phase C: threshold compaction (order-independent final result)
  {
    float thr = v16s - 1e-5f;
    for (int i=t; i<NCH*16; i+=256){
      if (svv[i] >= thr && (unsigned)sii[i] < (unsigned)N_MEM){
        int p = atomicAdd(&ncnt, 1);
        if (p < NCAND) candj[p] = sii[i];
      }
    }
  }
  __syncthreads();
  int NC = ncnt < NCAND ? ncnt : NCAND;
  // Phase D: f64 re-rank, candidates distributed across the 4 waves
  double qwl = qwd_g[q*64+l];
  double swl = sqrt(log1p(exp((double)fw[l])) + 1e-9);
  double qq  = qqd_g[q];
  int CM = (NC + 3) >> 2;
  for (int it=0; it<CM; it++){
    int c = it*4 + w;
    bool act = (c < NC);
    if (act){
      int j = candj[c];
      mdw[w][l] = (double)mi[(size_t)j*64 + l];
    }
    __syncthreads();
    double h = 0.0;
    if (act){
      double a0=0,a1=0,a2=0,a3=0;
      for (int d=0; d<64; d+=4){
        a0 = fma(mdw[w][d  ], (double)le_w1[(d  )*64+l], a0);
        a1 = fma(mdw[w][d+1], (double)le_w1[(d+1)*64+l], a1);
        a2 = fma(mdw[w][d+2], (double)le_w1[(d+2)*64+l], a2);
        a3 = fma(mdw[w][d+3], (double)le_w1[(d+3)*64+l], a3);
      }
      h = (a0+a1)+(a2+a3) + (double)le_b1[l];
      h = h>0.0 ? h : 0.0;
      hdw[w][l] = h;
    }
    __syncthreads();
    if (act){
      double a0=0,a1=0,a2=0,a3=0;
      for (int d=0; d<64; d+=4){
        a0 = fma(hdw[w][d  ], (double)le_w2[(d  )*64+l], a0);
        a1 = fma(hdw[w][d+1], (double)le_w2[(d+1)*64+l], a1);
        a2 = fma(hdw[w][d+2], (double)le_w2[(d+2)*64+l], a2);
        a3 = fma(hdw[w][d+3], (double)le_w2[(d+3)*64+l], a3);
      }
      double o  = (a0+a1)+(a2+a3) + (double)le_b2[l];
      double mw = o * swl;
      double mm2 = wave_sum_d(mw*mw);
      double dt  = wave_sum_d(mw*qwl);
      if (l==0) cd2[c] = qq + mm2 - 2.0*dt;
    }
    __syncthreads();
  }
  // Phase E (wave 0): f32-quantized raw + top-16 by (raw32 desc, idx asc)
  if (t < 64){
    float e32  = (float)exp((double)itp[0]);
    float sp32 = (float)log1p((double)e32);
    float t32  = __fadd_rn(sp32, 1e-9f);      // temp = softplus + EPS
    float dn32 = __fadd_rn(t32, 1e-9f);       // denom = temp + EPS
    double denom = (double)dn32;
    float rme; int jme;
    if (l < NC){
      double d2 = cd2[l]; if (d2 < 0.0) d2 = 0.0;
      float ratio32 = (float)(d2 / denom);
      rme = (float)exp(-(double)ratio32);
      jme = candj[l];
    } else { rme = -2.0f; jme = 0x7fffffff; }
    bool used = false;
    for (int it=0; it<16; it++){
      float a = used ? -2.0f : rme; int aj = jme; int ap = l;
      wave_argmax3(a, aj, ap);
      if (ap == l) used = true;
      if (l == it){ selr[it]=a; selj[it]=aj; }
    }
  }
  __syncthreads();
  // Phase F (wave 0): f64 softmax over quantized raws, gather, blend, refine
  if (t < 64){
    double raw = (l<16) ? (double)selr[l] : -1.0e300;
    double mv = raw;
    #pragma unroll
    for (int o=32;o;o>>=1){ double ov = __shfl_xor(mv,o,64); mv = ov>mv?ov:mv; }
    double e  = (l<16) ? exp(raw - mv) : 0.0;
    double se = wave_sum_d(e);
    double wgt = e / se;
    double lp[8] = {0,0,0,0,0,0,0,0};
    if (l < 16){
      const float* tr = mt + (size_t)selj[l]*8;
      #pragma unroll
      for (int tt=0; tt<8; tt++) lp[tt] = wgt * (double)tr[tt];
    }
    #pragma unroll
    for (int tt=0; tt<8; tt++) lp[tt] = wave_sum_d(lp[tt]);
    double g = ggd_g[q];
    double bl[8];
    #pragma unroll
    for (int tt=0; tt<8; tt++) bl[tt] = g*lp[tt] + (1.0-g)*gpd_g[q*8+tt];
    if (l < 32){
      double a = (double)rb1[l];
      #pragma unroll
      for (int tt=0; tt<8; tt++) a = fma(bl[tt], (double)rw1[tt*32+l], a);
      hh[l] = a>0.0?a:0.0;
    }
  }
  __syncthreads();
  if (t < 8){
    double a = (double)rb2[t];
    #pragma unroll
    for (int i=0; i<32; i++) a = fma(hh[i], (double)rw2[i*8+t], a);
    out[q*8+t] = (float)a;
  }
}

extern "C" void kernel_launch(void* const* d_in, const int* in_sizes, int n_in,
                              void* d_out, int out_size, void* d_ws, size_t ws_size,
                              hipStream_t stream)
{
  const float* x     = (const float*)d_in[0];
  const float* mi    = (const float*)d_in[1];
  const float* mt    = (const float*)d_in[2];
  const float* le_w1 = (const float*)d_in[3];
  const float* le_b1 = (const float*)d_in[4];
  const float* le_w2 = (const float*)d_in[5];
  const float* le_b2 = (const float*)d_in[6];
  const float* fw    = (const float*)d_in[7];
  const float* itp   = (const float*)d_in[8];
  const float* ge_w1 = (const float*)d_in[9];
  const float* ge_b1 = (const float*)d_in[10];
  const float* ge_w2 = (const float*)d_in[11];
  const float* ge_b2 = (const float*)d_in[12];
  const float* ge_w3 = (const float*)d_in[13];
  const float* ge_b3 = (const float*)d_in[14];
  const float* gr_w1 = (const float*)d_in[15];
  const float* gr_b1 = (const float*)d_in[16];
  const float* gr_w2 = (const float*)d_in[17];
  const float* gr_b2 = (const float*)d_in[18];
  const float* ga_w1 = (const float*)d_in[19];
  const float* ga_b1 = (const float*)d_in[20];
  const float* ga_w2 = (const float*)d_in[21];
  const float* ga_b2 = (const float*)d_in[22];
  const float* rh_w1 = (const float*)d_in[23];
  const float* rh_b1 = (const float*)d_in[24];
  const float* rh_w2 = (const float*)d_in[25];
  const float* rh_b2 = (const float*)d_in[26];

  // doubles first (8B alignment), then float/int region
  double* dws = (double*)d_ws;
  double* qwd = dws;                                // 1024*64
  double* qqd = qwd + (size_t)1024*64;              // 1024
  double* ggd = qqd + 1024;                         // 1024
  double* gpd = ggd + 1024;                         // 8192
  float*  fws = (float*)(gpd + 8192);
  float* mwT = fws;                                 // 64*NP
  float* mm  = mwT + (size_t)64*NP;                 // NP
  float* qwf = mm  + NP;                            // 1024*64
  float* tau = qwf + (size_t)1024*64;               // 1024
  float* tpv = tau + 1024;                          // 1024*128
  int*   tpi = (int*)(tpv + (size_t)1024*128);      // 1024*128
  float* cv  = (float*)(tpi + (size_t)1024*128);    // 1024*49*16
  int*   ci  = (int*)(cv + (size_t)1024*NCH*16);    // 1024*49*16

  k1_mem   <<<dim3(NP/128), dim3(128), 0, stream>>>(mi, le_w1, le_b1, le_w2, le_b2, fw, mwT, mm);
  k2_query <<<dim3(1024),   dim3(64),  0, stream>>>(x, le_w1, le_b1, le_w2, le_b2, fw,
                ge_w1, ge_b1, ge_w2, ge_b2, ge_w3, ge_b3,
                gr_w1, gr_b1, gr_w2, gr_b2,
                ga_w1, ga_b1, ga_w2, ga_b2,
                qwf, qwd, qqd, ggd, gpd);
  k_tau_a  <<<dim3(32,8),   dim3(256), 0, stream>>>(mwT, mm, qwf, tpv, tpi);
  k_tau_b  <<<dim3(1024),   dim3(64),  0, stream>>>(tpv, tpi, tau, cv, ci);
  k3_main  <<<dim3(32,47),  dim3(256), 0, stream>>>(mwT, mm, qwf, tau, cv, ci);
  k4_final <<<dim3(1024),   dim3(256), 0, stream>>>(cv, ci, qwd, qqd, ggd, gpd, mi, mt,
                le_w1, le_b1, le_w2, le_b2, fw, itp,
                rh_w1, rh_b1, rh_w2, rh_b2, (float*)d_out);
}